// Round 3
// baseline (226.719 us; speedup 1.0000x reference)
//
#include <hip/hip_runtime.h>
#include <hip/hip_bf16.h>

// Problem constants (from reference)
#define T_ROWS   8192
#define K_DIM    4096
#define N_INT    63
#define N_LEAF   64
#define NCLS     10

typedef __bf16 bf16x8 __attribute__((ext_vector_type(8)));
typedef __bf16 bf16x4 __attribute__((ext_vector_type(4)));
typedef float  f32x4  __attribute__((ext_vector_type(4)));

// ---------------------------------------------------------------------------
// Prep: W (63x4096 fp32) -> Wb (64x4096 bf16, row 63 zeroed); leaf_r[64];
// also zeroes the output accumulator (d_out is poisoned before every replay).
// ---------------------------------------------------------------------------
__global__ __launch_bounds__(256) void sdt_prep(
    const float* __restrict__ W,
    const float* __restrict__ leaf_dist,
    const float* __restrict__ class_reward,
    __bf16* __restrict__ Wb,
    float* __restrict__ leaf_r,
    float* __restrict__ out)
{
    int gid  = blockIdx.x * 256 + threadIdx.x;   // 65536 threads total
    int base = gid * 4;                          // element idx in 64x4096
    int n    = base >> 12;                       // row (4096 per row)
    bf16x4 v;
    if (n < N_INT) {
        const float4 w = *reinterpret_cast<const float4*>(W + base);
        v[0] = (__bf16)w.x; v[1] = (__bf16)w.y; v[2] = (__bf16)w.z; v[3] = (__bf16)w.w;
    } else {
        v[0] = (__bf16)0.0f; v[1] = (__bf16)0.0f; v[2] = (__bf16)0.0f; v[3] = (__bf16)0.0f;
    }
    *reinterpret_cast<bf16x4*>(Wb + base) = v;

    if (blockIdx.x == 0) {
        if (threadIdx.x < N_LEAF) {
            int i = threadIdx.x;
            float m = -1e30f;
            #pragma unroll
            for (int j = 0; j < NCLS; ++j) m = fmaxf(m, leaf_dist[i * NCLS + j]);
            float s = 0.0f, d = 0.0f;
            #pragma unroll
            for (int j = 0; j < NCLS; ++j) {
                float e = expf(leaf_dist[i * NCLS + j] - m);
                s += e;
                d += e * class_reward[j];
            }
            leaf_r[i] = d / s;
        } else if (threadIdx.x == N_LEAF) {
            out[0] = 0.0f;   // main() atomicAdds into this (stream-ordered after prep)
        }
    }
}

// ---------------------------------------------------------------------------
// Main: fused GEMM (bf16 MFMA) + sigmoid + tree propagation + reduce
// 1024 blocks x 256 threads (4 waves = 4 blocks/CU = 16 waves/CU).
// BM=16 rows/block, 4-way wave-split K (1024 each), explicit A-reg
// double-buffer so each wave keeps ~4 KB of X in flight past the MFMA chain.
// ---------------------------------------------------------------------------
__global__ __launch_bounds__(256, 4) void sdt_main(
    const float* __restrict__ X,       // 8192 x 4096 fp32
    const __bf16* __restrict__ Wb,     // 64 x 4096 bf16
    const float* __restrict__ b,       // 63
    const float* __restrict__ beta,    // 63
    const float* __restrict__ leaf_r,  // 64
    float* __restrict__ out)           // scalar
{
    // Padded stride 65 breaks the 4-quad bank alias on the accumulator dump.
    __shared__ float red[4 * 16 * 65];   // per-wave C copies (16.6 KB)
    __shared__ float Pbuf[16 * 64];      // sigmoid'd node probs per row
    __shared__ float sred[4];

    const int tid  = threadIdx.x;
    const int wid  = tid >> 6;
    const int lane = tid & 63;
    const int m16  = lane & 15;          // A row within tile / C col
    const int q    = lane >> 4;          // quad

    const int row0 = blockIdx.x * 16;
    const int kbase = wid * (K_DIM / 4); // 1024 K per wave, 32 iters of k32

    // A stream: f32x4 units, stride 8 units (32 floats) per iteration.
    const f32x4* Ap = reinterpret_cast<const f32x4*>(
        X + (size_t)(row0 + m16) * K_DIM + kbase + q * 8);
    // B base pointers per 16-col group (L2-hot).
    const __bf16* B0 = Wb + (size_t)(0 * 16 + m16) * K_DIM + kbase + q * 8;
    const __bf16* B1 = Wb + (size_t)(1 * 16 + m16) * K_DIM + kbase + q * 8;
    const __bf16* B2 = Wb + (size_t)(2 * 16 + m16) * K_DIM + kbase + q * 8;
    const __bf16* B3 = Wb + (size_t)(3 * 16 + m16) * K_DIM + kbase + q * 8;

    f32x4 acc[4];
    #pragma unroll
    for (int g = 0; g < 4; ++g) acc[g] = (f32x4){0.0f, 0.0f, 0.0f, 0.0f};

    // Prologue: first A fragment in flight.
    f32x4 c0 = __builtin_nontemporal_load(Ap);
    f32x4 c1 = __builtin_nontemporal_load(Ap + 1);

    #pragma unroll 2
    for (int it = 0; it < 32; ++it) {
        f32x4 n0, n1;
        if (it < 31) {   // prefetch next iteration's A before this MFMA chain
            n0 = __builtin_nontemporal_load(Ap + (it + 1) * 8);
            n1 = __builtin_nontemporal_load(Ap + (it + 1) * 8 + 1);
        }
        bf16x8 af;
        af[0] = (__bf16)c0[0]; af[1] = (__bf16)c0[1];
        af[2] = (__bf16)c0[2]; af[3] = (__bf16)c0[3];
        af[4] = (__bf16)c1[0]; af[5] = (__bf16)c1[1];
        af[6] = (__bf16)c1[2]; af[7] = (__bf16)c1[3];
        const int ko = it * 32;
        const bf16x8 bf0 = *reinterpret_cast<const bf16x8*>(B0 + ko);
        const bf16x8 bf1 = *reinterpret_cast<const bf16x8*>(B1 + ko);
        const bf16x8 bf2 = *reinterpret_cast<const bf16x8*>(B2 + ko);
        const bf16x8 bf3 = *reinterpret_cast<const bf16x8*>(B3 + ko);
        acc[0] = __builtin_amdgcn_mfma_f32_16x16x32_bf16(af, bf0, acc[0], 0, 0, 0);
        acc[1] = __builtin_amdgcn_mfma_f32_16x16x32_bf16(af, bf1, acc[1], 0, 0, 0);
        acc[2] = __builtin_amdgcn_mfma_f32_16x16x32_bf16(af, bf2, acc[2], 0, 0, 0);
        acc[3] = __builtin_amdgcn_mfma_f32_16x16x32_bf16(af, bf3, acc[3], 0, 0, 0);
        c0 = n0; c1 = n1;
    }

    // Dump per-wave partial C: C[row=q*4+r][col=g*16+m16]
    #pragma unroll
    for (int g = 0; g < 4; ++g)
        #pragma unroll
        for (int r = 0; r < 4; ++r)
            red[(wid * 16 + q * 4 + r) * 65 + g * 16 + m16] = acc[g][r];
    __syncthreads();

    // Reduce 4 wave copies -> logits -> P = sigmoid(beta*(l+b))
    for (int e = tid; e < 16 * 64; e += 256) {
        const int r = e >> 6, c = e & 63;
        float s = 0.0f;
        #pragma unroll
        for (int w = 0; w < 4; ++w) s += red[(w * 16 + r) * 65 + c];
        float P = 0.0f;
        if (c < N_INT) {
            const float z = beta[c] * (s + b[c]);
            P = 1.0f / (1.0f + __expf(-z));
        }
        Pbuf[r * 64 + c] = P;
    }
    __syncthreads();

    // Tree: thread -> (row = tid>>4, 4 leaves). leaf path product * leaf_r.
    const int row = tid >> 4;
    const int t16 = tid & 15;
    float score = 0.0f;
    #pragma unroll
    for (int u = 0; u < 4; ++u) {
        const int leaf = t16 * 4 + u;
        float prod = 1.0f;
        #pragma unroll
        for (int k = 0; k < 6; ++k) {
            const int node = ((1 << k) - 1) + (leaf >> (6 - k));
            const float p  = Pbuf[row * 64 + node];
            const int bit  = (leaf >> (5 - k)) & 1;
            prod *= bit ? (1.0f - p) : p;
        }
        score += prod * leaf_r[leaf];
    }

    // Block reduction -> one atomicAdd per block
    #pragma unroll
    for (int off = 32; off > 0; off >>= 1)
        score += __shfl_down(score, off, 64);
    if (lane == 0) sred[wid] = score;
    __syncthreads();
    if (tid == 0) {
        float s = sred[0] + sred[1] + sred[2] + sred[3];
        atomicAdd(out, s);
    }
}

// ---------------------------------------------------------------------------
extern "C" void kernel_launch(void* const* d_in, const int* in_sizes, int n_in,
                              void* d_out, int out_size, void* d_ws, size_t ws_size,
                              hipStream_t stream)
{
    const float* X           = (const float*)d_in[0];
    const float* W           = (const float*)d_in[1];
    const float* b           = (const float*)d_in[2];
    const float* beta        = (const float*)d_in[3];
    const float* leaf_dist   = (const float*)d_in[4];
    const float* class_rew   = (const float*)d_in[5];
    float* out               = (float*)d_out;

    __bf16* Wb    = (__bf16*)d_ws;                                  // 64*4096*2 B
    float*  leafr = (float*)((char*)d_ws + (size_t)N_LEAF * K_DIM * 2);

    sdt_prep<<<256, 256, 0, stream>>>(W, leaf_dist, class_rew, Wb, leafr, out);
    sdt_main<<<T_ROWS / 16, 256, 0, stream>>>(X, Wb, b, beta, leafr, out);
}

// Round 4
// 218.821 us; speedup vs baseline: 1.0361x; 1.0361x over previous
//
#include <hip/hip_runtime.h>
#include <hip/hip_bf16.h>

// Problem constants (from reference)
#define T_ROWS   8192
#define K_DIM    4096
#define N_INT    63
#define N_LEAF   64
#define NCLS     10

// Main-kernel tiling
#define BM       16                  // rows per block
#define CHUNK    512                 // K floats per staged chunk
#define NCHUNK   (K_DIM / CHUNK)     // 8
#define ASTRIDE  516                 // padded row stride (floats): 16B-aligned, bank +4 mod 32

typedef __bf16 bf16x8 __attribute__((ext_vector_type(8)));
typedef __bf16 bf16x4 __attribute__((ext_vector_type(4)));
typedef float  f32x4  __attribute__((ext_vector_type(4)));

// Async global->LDS, 16 B/lane, contiguous (wave-uniform LDS base + lane*16).
#define GLOAD_LDS16(g, l) __builtin_amdgcn_global_load_lds(              \
    (const __attribute__((address_space(1))) void*)(g),                  \
    (__attribute__((address_space(3))) void*)(l), 16, 0, 0)

// ---------------------------------------------------------------------------
// Prep: W (63x4096 fp32) -> Wb (64x4096 bf16, row 63 zeroed); leaf_r[64];
// also zeroes the output accumulator (d_out is poisoned before every replay).
// ---------------------------------------------------------------------------
__global__ __launch_bounds__(256) void sdt_prep(
    const float* __restrict__ W,
    const float* __restrict__ leaf_dist,
    const float* __restrict__ class_reward,
    __bf16* __restrict__ Wb,
    float* __restrict__ leaf_r,
    float* __restrict__ out)
{
    int gid  = blockIdx.x * 256 + threadIdx.x;   // 65536 threads total
    int base = gid * 4;                          // element idx in 64x4096
    int n    = base >> 12;                       // row (4096 per row)
    bf16x4 v;
    if (n < N_INT) {
        const float4 w = *reinterpret_cast<const float4*>(W + base);
        v[0] = (__bf16)w.x; v[1] = (__bf16)w.y; v[2] = (__bf16)w.z; v[3] = (__bf16)w.w;
    } else {
        v[0] = (__bf16)0.0f; v[1] = (__bf16)0.0f; v[2] = (__bf16)0.0f; v[3] = (__bf16)0.0f;
    }
    *reinterpret_cast<bf16x4*>(Wb + base) = v;

    if (blockIdx.x == 0) {
        if (threadIdx.x < N_LEAF) {
            int i = threadIdx.x;
            float m = -1e30f;
            #pragma unroll
            for (int j = 0; j < NCLS; ++j) m = fmaxf(m, leaf_dist[i * NCLS + j]);
            float s = 0.0f, d = 0.0f;
            #pragma unroll
            for (int j = 0; j < NCLS; ++j) {
                float e = expf(leaf_dist[i * NCLS + j] - m);
                s += e;
                d += e * class_reward[j];
            }
            leaf_r[i] = d / s;
        } else if (threadIdx.x == N_LEAF) {
            out[0] = 0.0f;   // main() atomicAdds into this (stream-ordered after prep)
        }
    }
}

// ---------------------------------------------------------------------------
// Main: m97-style async-staged GEMM + sigmoid + tree + reduce.
// 512 blocks x 256 threads (4 waves). 2 blocks/CU (66 KB LDS each).
// Per chunk: 32x global_load_lds_dwordx4 (1 KB contiguous each) double-
// buffered; 4-way wave-split K within the chunk; B (Wb) read from L2.
// ---------------------------------------------------------------------------
__global__ __launch_bounds__(256, 2) void sdt_main(
    const float* __restrict__ X,       // 8192 x 4096 fp32
    const __bf16* __restrict__ Wb,     // 64 x 4096 bf16
    const float* __restrict__ b,       // 63
    const float* __restrict__ beta,    // 63
    const float* __restrict__ leaf_r,  // 64
    float* __restrict__ out)           // scalar
{
    // Double-buffered A tile; epilogue scratch aliases buffer 0's region
    // (epilogue only ever runs concurrently with reads of buffer 1).
    __shared__ float Ash[2 * BM * ASTRIDE];      // 66048 B
    __shared__ float sred[4];
    float* red  = Ash;                            // [4][16][65] = 4160 floats
    float* Pbuf = Ash + 4 * 16 * 65;              // [16][64]    = 1024 floats

    const int tid  = threadIdx.x;
    const int wid  = tid >> 6;
    const int lane = tid & 63;
    const int m16  = lane & 15;          // A row within tile / C col
    const int q    = lane >> 4;          // quad

    const int row0   = blockIdx.x * BM;
    const int kslice = wid * (CHUNK / 4);        // 128 K per wave within chunk

    // B base pointers per 16-col group (L2-hot), at this wave's k-slice.
    const __bf16* B0 = Wb + (size_t)(0 * 16 + m16) * K_DIM + kslice + q * 8;
    const __bf16* B1 = Wb + (size_t)(1 * 16 + m16) * K_DIM + kslice + q * 8;
    const __bf16* B2 = Wb + (size_t)(2 * 16 + m16) * K_DIM + kslice + q * 8;
    const __bf16* B3 = Wb + (size_t)(3 * 16 + m16) * K_DIM + kslice + q * 8;

    f32x4 acc[4];
    #pragma unroll
    for (int g = 0; g < 4; ++g) acc[g] = (f32x4){0.0f, 0.0f, 0.0f, 0.0f};

    // Stage chunk c into buffer buf: 32 segs of 1 KB (row, half), 8 per wave.
    auto stage = [&](int buf, int c) {
        #pragma unroll
        for (int i = 0; i < 8; ++i) {
            const int seg  = wid * 8 + i;        // 0..31
            const int row  = seg >> 1;
            const int half = seg & 1;
            const float* g = X + (size_t)(row0 + row) * K_DIM
                               + c * CHUNK + half * 256 + lane * 4;
            float* l = Ash + buf * (BM * ASTRIDE) + row * ASTRIDE + half * 256;
            GLOAD_LDS16(g, l);
        }
    };

    stage(0, 0);

    for (int c = 0; c < NCHUNK; ++c) {
        __syncthreads();                         // drains vmcnt: chunk c visible
        if (c + 1 < NCHUNK) stage((c + 1) & 1, c + 1);

        const float* Ab = Ash + (c & 1) * (BM * ASTRIDE) + (size_t)m16 * ASTRIDE;
        const int kg = c * CHUNK;                // global k of chunk start
        #pragma unroll
        for (int s = 0; s < 4; ++s) {
            const int kc = kslice + s * 32 + q * 8;     // k within chunk
            const f32x4 a0 = *reinterpret_cast<const f32x4*>(Ab + kc);
            const f32x4 a1 = *reinterpret_cast<const f32x4*>(Ab + kc + 4);
            bf16x8 af;
            af[0] = (__bf16)a0[0]; af[1] = (__bf16)a0[1];
            af[2] = (__bf16)a0[2]; af[3] = (__bf16)a0[3];
            af[4] = (__bf16)a1[0]; af[5] = (__bf16)a1[1];
            af[6] = (__bf16)a1[2]; af[7] = (__bf16)a1[3];
            const int ko = kg + s * 32;                  // B offset from kslice base
            const bf16x8 bf0 = *reinterpret_cast<const bf16x8*>(B0 + ko);
            const bf16x8 bf1 = *reinterpret_cast<const bf16x8*>(B1 + ko);
            const bf16x8 bf2 = *reinterpret_cast<const bf16x8*>(B2 + ko);
            const bf16x8 bf3 = *reinterpret_cast<const bf16x8*>(B3 + ko);
            acc[0] = __builtin_amdgcn_mfma_f32_16x16x32_bf16(af, bf0, acc[0], 0, 0, 0);
            acc[1] = __builtin_amdgcn_mfma_f32_16x16x32_bf16(af, bf1, acc[1], 0, 0, 0);
            acc[2] = __builtin_amdgcn_mfma_f32_16x16x32_bf16(af, bf2, acc[2], 0, 0, 0);
            acc[3] = __builtin_amdgcn_mfma_f32_16x16x32_bf16(af, bf3, acc[3], 0, 0, 0);
        }
    }

    // Dump per-wave partial C into red (aliases buf0; disjoint from buf1,
    // which is the only region chunk-7 compute reads).
    #pragma unroll
    for (int g = 0; g < 4; ++g)
        #pragma unroll
        for (int r = 0; r < 4; ++r)
            red[(wid * 16 + q * 4 + r) * 65 + g * 16 + m16] = acc[g][r];
    __syncthreads();

    // Reduce 4 wave copies -> logits -> P = sigmoid(beta*(l+b))
    for (int e = tid; e < 16 * 64; e += 256) {
        const int r = e >> 6, c = e & 63;
        float s = 0.0f;
        #pragma unroll
        for (int w = 0; w < 4; ++w) s += red[(w * 16 + r) * 65 + c];
        float P = 0.0f;
        if (c < N_INT) {
            const float z = beta[c] * (s + b[c]);
            P = 1.0f / (1.0f + __expf(-z));
        }
        Pbuf[r * 64 + c] = P;
    }
    __syncthreads();

    // Tree: thread -> (row = tid>>4, 4 leaves). leaf path product * leaf_r.
    const int row = tid >> 4;
    const int t16 = tid & 15;
    float score = 0.0f;
    #pragma unroll
    for (int u = 0; u < 4; ++u) {
        const int leaf = t16 * 4 + u;
        float prod = 1.0f;
        #pragma unroll
        for (int k = 0; k < 6; ++k) {
            const int node = ((1 << k) - 1) + (leaf >> (6 - k));
            const float p  = Pbuf[row * 64 + node];
            const int bit  = (leaf >> (5 - k)) & 1;
            prod *= bit ? (1.0f - p) : p;
        }
        score += prod * leaf_r[leaf];
    }

    // Block reduction -> one atomicAdd per block
    #pragma unroll
    for (int off = 32; off > 0; off >>= 1)
        score += __shfl_down(score, off, 64);
    if (lane == 0) sred[wid] = score;
    __syncthreads();
    if (tid == 0) {
        float s = sred[0] + sred[1] + sred[2] + sred[3];
        atomicAdd(out, s);
    }
}

// ---------------------------------------------------------------------------
extern "C" void kernel_launch(void* const* d_in, const int* in_sizes, int n_in,
                              void* d_out, int out_size, void* d_ws, size_t ws_size,
                              hipStream_t stream)
{
    const float* X           = (const float*)d_in[0];
    const float* W           = (const float*)d_in[1];
    const float* b           = (const float*)d_in[2];
    const float* beta        = (const float*)d_in[3];
    const float* leaf_dist   = (const float*)d_in[4];
    const float* class_rew   = (const float*)d_in[5];
    float* out               = (float*)d_out;

    __bf16* Wb    = (__bf16*)d_ws;                                  // 64*4096*2 B
    float*  leafr = (float*)((char*)d_ws + (size_t)N_LEAF * K_DIM * 2);

    sdt_prep<<<256, 256, 0, stream>>>(W, leaf_dist, class_rew, Wb, leafr, out);
    sdt_main<<<T_ROWS / BM, 256, 0, stream>>>(X, Wb, b, beta, leafr, out);
}